// Round 9
// baseline (30.358 us; speedup 1.0000x reference)
//
#include <hip/hip_runtime.h>

// SpacialSeparation: sum over j>i of (||o_i - o_j||^2)^(1/4) * (labels differ ? -1 : 5)
// b = 8192, d = 64, fp32 in, fp32 scalar out.
//
// Round 8: XOR-swizzled unpadded LDS (exactly 32 KiB) -> 5 blocks/CU (was 4).
//   Layout: 16B chunk c of row r lives at slot (c ^ (r&7)) -> fragment reads and
//   staging writes are both bank-conflict-free with zero padding.
//   wsum folded into the panel LDS (reused behind a barrier) to keep 32768 B.
//   Rest identical to r7: K=64 Gram, triangular grid, partials + reduce kernel.

typedef __bf16 bf16x8 __attribute__((ext_vector_type(8)));
typedef float  f32x4  __attribute__((ext_vector_type(4)));
typedef int    i32x4  __attribute__((ext_vector_type(4)));

#define BT    128
#define DK    64
#define PANEL (128 * DK)          // 8192 elements = 16,384 B per panel

__device__ __forceinline__ float qroot(float x) {          // x^(1/4)
    return __builtin_amdgcn_sqrtf(__builtin_amdgcn_sqrtf(x));
}
__device__ __forceinline__ unsigned short rne_bf16(float v) {
    const unsigned u = __builtin_bit_cast(unsigned, v);
    return (unsigned short)((u + 0x7fffu + ((u >> 16) & 1u)) >> 16);
}

// ---- prep: fp32 -> bf16 (RNE) + row squared norms of the rounded values ----
__global__ __launch_bounds__(256)
void ss_prep(const float* __restrict__ O, unsigned short* __restrict__ Obf,
             float* __restrict__ sqb) {
    const int row  = blockIdx.x * 4 + (threadIdx.x >> 6);
    const int lane = threadIdx.x & 63;
    const float v = O[(size_t)row * 64 + lane];
    const unsigned short w = rne_bf16(v);
    Obf[(size_t)row * 64 + lane] = w;
    const float wf = __builtin_bit_cast(float, (unsigned)w << 16);
    float s = wf * wf;
    #pragma unroll
    for (int off = 32; off; off >>= 1) s += __shfl_xor(s, off);
    if (lane == 0) sqb[row] = s;
}

// ---- main: swizzled-LDS Gram + epilogue; per-block partial store ----
__global__ __launch_bounds__(256, 4)
void ss_mfma(const unsigned short* __restrict__ Obf, const float* __restrict__ sqb,
             const int* __restrict__ L, float* __restrict__ partials, int nt) {
    // decode linear block id -> upper-tri tile (ti, tj), ti <= tj
    const int t = blockIdx.x;
    const float fnt = (float)nt + 0.5f;
    int ti = (int)floorf(fnt - sqrtf(fnt * fnt - 2.0f * (float)t));
    if (ti < 0) ti = 0;
    if (ti > nt - 1) ti = nt - 1;
    while (ti > 0 && ti * nt - (ti * (ti - 1)) / 2 > t) --ti;
    while ((ti + 1) * nt - ((ti + 1) * ti) / 2 <= t) ++ti;
    const int tj = ti + (t - (ti * nt - (ti * (ti - 1)) / 2));

    const int tid  = threadIdx.x;
    const int wave = tid >> 6, lane = tid & 63;
    const int wr = wave >> 1, wc = wave & 1;
    const bool diag = (ti == tj);

    __shared__ unsigned short lds[2 * PANEL];      // 32,768 B exactly

    // ---- stage both panels, swizzled: chunk c of row r -> slot (c ^ (r&7)) ----
    {
        const unsigned short* srcA = Obf + (size_t)(ti * BT) * DK;  // contiguous panels
        const unsigned short* srcB = Obf + (size_t)(tj * BT) * DK;
        bf16x8 ra[4], rb[4];
        #pragma unroll
        for (int k = 0; k < 4; ++k) {
            const int id = k * 256 + tid;          // 16B-chunk id, 0..1023
            ra[k] = *(const bf16x8*)(srcA + id * 8);
            rb[k] = *(const bf16x8*)(srcB + id * 8);
        }
        #pragma unroll
        for (int k = 0; k < 4; ++k) {
            const int id   = k * 256 + tid;
            const int row  = id >> 3, c = id & 7;
            const int slot = (c ^ (row & 7)) * 8;
            *(bf16x8*)(&lds[row * DK + slot])         = ra[k];
            *(bf16x8*)(&lds[PANEL + row * DK + slot]) = rb[k];
        }
    }
    __syncthreads();

    const int lrow = lane & 15;
    const int kq   = lane >> 4;          // 0..3
    const int r0   = ti * BT + wr * 64;  // global i-row base
    const int x0   = (kq       ^ (lrow & 7)) * 8;   // swizzled chunk offsets
    const int x1   = ((kq + 4) ^ (lrow & 7)) * 8;

    float accs = 0.0f;

    if (!(diag && (wc < wr))) {          // skip fully-lower subtile of diag blocks
        // i-side metadata (C/D rows: kq*4 + r  [m89])
        f32x4 sqi[4]; i32x4 li[4];
        #pragma unroll
        for (int f = 0; f < 4; ++f) {
            const int ib = r0 + f * 16 + (kq << 2);
            sqi[f] = *(const f32x4*)(sqb + ib);
            li[f]  = *(const i32x4*)(L + ib);
        }
        const bool masked = diag && (wr == wc);

        // ---- A fragments from swizzled LDS ----
        bf16x8 afr[4][2];
        #pragma unroll
        for (int i = 0; i < 4; ++i) {
            const int rbase = (wr * 64 + i * 16 + lrow) * DK;
            afr[i][0] = *(const bf16x8*)(&lds[rbase + x0]);
            afr[i][1] = *(const bf16x8*)(&lds[rbase + x1]);
        }

        #pragma unroll
        for (int jh = 0; jh < 2; ++jh) {            // two 64x32 j-halves
            bf16x8 bfr[2][2];
            #pragma unroll
            for (int g = 0; g < 2; ++g) {
                const int rbase = PANEL + (wc * 64 + jh * 32 + g * 16 + lrow) * DK;
                bfr[g][0] = *(const bf16x8*)(&lds[rbase + x0]);
                bfr[g][1] = *(const bf16x8*)(&lds[rbase + x1]);
            }

            f32x4 acc[4][2];
            #pragma unroll
            for (int i = 0; i < 4; ++i)
                #pragma unroll
                for (int g = 0; g < 2; ++g)
                    acc[i][g] = (f32x4){0.f, 0.f, 0.f, 0.f};

            #pragma unroll
            for (int i = 0; i < 4; ++i)
                #pragma unroll
                for (int g = 0; g < 2; ++g) {
                    acc[i][g] = __builtin_amdgcn_mfma_f32_16x16x32_bf16(afr[i][0], bfr[g][0], acc[i][g], 0, 0, 0);
                    acc[i][g] = __builtin_amdgcn_mfma_f32_16x16x32_bf16(afr[i][1], bfr[g][1], acc[i][g], 0, 0, 0);
                }

            // ---- epilogue: d2 = si + sj - 2*gram ----
            const int c0 = tj * BT + wc * 64 + jh * 32;
            #pragma unroll
            for (int g = 0; g < 2; ++g) {
                const int j    = c0 + g * 16 + lrow;
                const float sj = sqb[j];
                const int  ljv = L[j];
                if (masked) {
                    #pragma unroll
                    for (int fi = 0; fi < 4; ++fi) {
                        const int ib = r0 + fi * 16 + (kq << 2);
                        #pragma unroll
                        for (int r = 0; r < 4; ++r) {
                            float d2 = fmaf(-2.0f, acc[fi][g][r], sqi[fi][r] + sj);
                            d2 = fmaxf(d2, 0.0f);
                            const float dist = qroot(d2);
                            const float fac  = (li[fi][r] != ljv) ? -1.0f : 5.0f;
                            accs += (j > ib + r) ? dist * fac : 0.0f;
                        }
                    }
                } else {
                    #pragma unroll
                    for (int fi = 0; fi < 4; ++fi) {
                        #pragma unroll
                        for (int r = 0; r < 4; ++r) {
                            float d2 = fmaf(-2.0f, acc[fi][g][r], sqi[fi][r] + sj);
                            d2 = fmaxf(d2, 0.0f);
                            const float dist = qroot(d2);
                            const float fac  = (li[fi][r] != ljv) ? -1.0f : 5.0f;
                            accs = fmaf(dist, fac, accs);
                        }
                    }
                }
            }
        }
    }

    // ---- block reduction -> plain partials store (LDS reused as scratch) ----
    #pragma unroll
    for (int off = 32; off > 0; off >>= 1) accs += __shfl_down(accs, off);
    __syncthreads();                       // all LDS fragment reads done
    float* fsc = (float*)lds;
    if (lane == 0) fsc[wave] = accs;
    __syncthreads();
    if (tid == 0) partials[t] = (fsc[0] + fsc[1]) + (fsc[2] + fsc[3]);
}

__global__ void ss_reduce_kernel(const float* __restrict__ partials, int n,
                                 float* __restrict__ out) {
    __shared__ float s[4];
    const int tid = threadIdx.x;
    float acc = 0.0f;
    for (int idx = tid; idx < n; idx += 256) acc += partials[idx];
    #pragma unroll
    for (int off = 32; off > 0; off >>= 1) acc += __shfl_down(acc, off);
    if ((tid & 63) == 0) s[tid >> 6] = acc;
    __syncthreads();
    if (tid == 0) out[0] = (s[0] + s[1]) + (s[2] + s[3]);
}

extern "C" void kernel_launch(void* const* d_in, const int* in_sizes, int n_in,
                              void* d_out, int out_size, void* d_ws, size_t ws_size,
                              hipStream_t stream) {
    const float* O = (const float*)d_in[0];   // [b, 64] fp32
    const int*   L = (const int*)d_in[1];     // [b] int32
    float* out = (float*)d_out;               // scalar fp32

    const int b    = in_sizes[1];             // 8192
    const int nt   = b / BT;                  // 64
    const int ntri = nt * (nt + 1) / 2;       // 2080

    // workspace layout
    char* ws = (char*)d_ws;
    float*          partials = (float*)ws;                          // ntri floats
    float*          sqb      = (float*)(ws + (64 << 10));           // b floats
    unsigned short* Obf      = (unsigned short*)(ws + (128 << 10)); // b*64 bf16

    ss_prep<<<b / 4, 256, 0, stream>>>(O, Obf, sqb);
    ss_mfma<<<ntri, 256, 0, stream>>>(Obf, sqb, L, partials, nt);
    ss_reduce_kernel<<<1, 256, 0, stream>>>(partials, ntri, out);
}